// Round 12
// baseline (825.849 us; speedup 1.0000x reference)
//
#include <hip/hip_runtime.h>
#include <hip/hip_bf16.h>

// Problem constants (fixed by setup_inputs)
#define TT    2209          // 47*47 relative-position table entries
#define NB    32            // batch
#define NH    16            // heads
#define ND    512           // RPB hidden dim
#define WH    24            // window height/width
#define NW    576           // 24*24 window tokens
#define NP    577           // NW + num_prefix_tokens(=1)
#define PLANE (NP * NP)     // 332929 floats per (b,h) output plane

// ---------------------------------------------------------------------------
// Stage 1: bias_t[b][h][t] = (relu((coords_table[t] + pos[b]) @ W1 + b1) @ W2)[h]
// (unchanged from the measured 730/733 µs runs)
// ---------------------------------------------------------------------------
__global__ __launch_bounds__(256) void cpb_mlp(
    const float* __restrict__ glob_pos,     // (1, 32, 4)
    const float* __restrict__ coords_table, // (2209, 2)
    const float* __restrict__ W1,           // (2, 512)
    const float* __restrict__ b1,           // (512,)
    const float* __restrict__ W2,           // (512, 16)
    float* __restrict__ bias_t)             // (32, 16, 2209) scratch
{
    __shared__ float sW13[ND][4];           // {W1row0, W1row1, b1, pad} — 8 KB
    __shared__ float sW2[ND][NH];           // 32 KB

    const int tid = threadIdx.x;
    for (int d = tid; d < ND; d += 256) {
        float4 v;
        v.x = W1[d];            // W1[0][d]
        v.y = W1[ND + d];       // W1[1][d]
        v.z = b1[d];
        v.w = 0.0f;
        *reinterpret_cast<float4*>(&sW13[d][0]) = v;
    }
    for (int i = tid; i < ND * NH / 4; i += 256) {
        reinterpret_cast<float4*>(&sW2[0][0])[i] =
            reinterpret_cast<const float4*>(W2)[i];
    }
    __syncthreads();

    const unsigned gid  = blockIdx.x * 256u + tid;
    const bool     live = gid < (unsigned)(NB * TT);
    const unsigned b    = live ? gid / TT : 0u;
    const unsigned t    = live ? gid - b * TT : 0u;

    const float g0 = glob_pos[b * 4 + 0];
    const float g1 = glob_pos[b * 4 + 1];
    const float g2 = glob_pos[b * 4 + 2];
    const float g3 = glob_pos[b * 4 + 3];
    float px = g2 / g0 * 8.0f;
    float py = g3 / g1 * 8.0f;
    px = copysignf(log2f(fabsf(px) + 1.0f) * (1.0f / 3.0f), px) * 2.0f - 1.0f;
    py = copysignf(log2f(fabsf(py) + 1.0f) * (1.0f / 3.0f), py) * 2.0f - 1.0f;

    const float tx = coords_table[t * 2 + 0] + px;
    const float ty = coords_table[t * 2 + 1] + py;

    float acc[NH];
#pragma unroll
    for (int h = 0; h < NH; ++h) acc[h] = 0.0f;

#pragma unroll 1
    for (int d0 = 0; d0 < ND; d0 += 4) {
        float hv[4];
#pragma unroll
        for (int k = 0; k < 4; ++k) {
            const float4 w = *reinterpret_cast<const float4*>(&sW13[d0 + k][0]);
            hv[k] = fmaxf(fmaf(tx, w.x, fmaf(ty, w.y, w.z)), 0.0f);
        }
#pragma unroll
        for (int k = 0; k < 4; ++k) {
            const float4 w0 = *reinterpret_cast<const float4*>(&sW2[d0 + k][0]);
            const float4 w1 = *reinterpret_cast<const float4*>(&sW2[d0 + k][4]);
            const float4 w2 = *reinterpret_cast<const float4*>(&sW2[d0 + k][8]);
            const float4 w3 = *reinterpret_cast<const float4*>(&sW2[d0 + k][12]);
            acc[0]  = fmaf(hv[k], w0.x, acc[0]);   acc[1]  = fmaf(hv[k], w0.y, acc[1]);
            acc[2]  = fmaf(hv[k], w0.z, acc[2]);   acc[3]  = fmaf(hv[k], w0.w, acc[3]);
            acc[4]  = fmaf(hv[k], w1.x, acc[4]);   acc[5]  = fmaf(hv[k], w1.y, acc[5]);
            acc[6]  = fmaf(hv[k], w1.z, acc[6]);   acc[7]  = fmaf(hv[k], w1.w, acc[7]);
            acc[8]  = fmaf(hv[k], w2.x, acc[8]);   acc[9]  = fmaf(hv[k], w2.y, acc[9]);
            acc[10] = fmaf(hv[k], w2.z, acc[10]);  acc[11] = fmaf(hv[k], w2.w, acc[11]);
            acc[12] = fmaf(hv[k], w3.x, acc[12]);  acc[13] = fmaf(hv[k], w3.y, acc[13]);
            acc[14] = fmaf(hv[k], w3.z, acc[14]);  acc[15] = fmaf(hv[k], w3.w, acc[15]);
        }
    }

    if (live) {
#pragma unroll
        for (int h = 0; h < NH; ++h) {
            bias_t[(b * NH + h) * TT + t] = acc[h];
        }
    }
}

// ---------------------------------------------------------------------------
// Stage 2: plane-aligned decomposition. 8 blocks per (b,h) plane, 512 threads.
// Each block stages exactly ONE 8.8 KB plane in LDS (no pA/pB select), then
// streams an aligned float4 body + <=3 scalar head/tail elements.
// idx = 1104 + a(i-1) - a(j-1), a(t) = t + 23*((t*2731)>>16)  (exact, t<=576).
// 512-thread blocks -> 4 blocks/CU = 32 waves/CU full occupancy @ 8.8 KB LDS.
// ---------------------------------------------------------------------------
#define CHUNK_ELEMS 41620u              // per-block plane-local span (div by 4)

__device__ __forceinline__ float cpb_val(const float* __restrict__ sP,
                                         unsigned i, unsigned j)
{
    const unsigned qi = i ? i - 1u : 0u;
    const unsigned tj = j ? j - 1u : 0u;
    const unsigned ai = qi + 23u * ((qi * 2731u) >> 16);   // a(qi)
    const unsigned aj = tj + 23u * ((tj * 2731u) >> 16);   // a(tj)
    const float v = sP[1104u + ai - aj];                   // in [0, 2209)
    return (i != 0u && j != 0u) ? v : 0.0f;
}

__global__ __launch_bounds__(512) void cpb_scatter(
    const float* __restrict__ bias_t, // (32, 16, 2209)
    float* __restrict__ out)          // (32, 16, 577, 577) flat
{
    const unsigned bx  = blockIdx.x;
    const unsigned p   = bx >> 3;               // plane = b*16 + h
    const unsigned c   = bx & 7u;               // chunk within plane
    const unsigned tid = threadIdx.x;

    __shared__ float sP[TT];                    // 8836 B
    const float* __restrict__ pl = bias_t + (size_t)p * TT;
    for (unsigned x = tid; x < (unsigned)TT; x += 512u) sP[x] = pl[x];
    __syncthreads();

    const unsigned lbeg = c * CHUNK_ELEMS;                       // plane-local
    const unsigned lend = min(lbeg + CHUNK_ELEMS, (unsigned)PLANE);
    const size_t   gofs = (size_t)p * PLANE;

    // alignment of the global start of this chunk
    const unsigned galign = (unsigned)((gofs + lbeg) & 3u);
    const unsigned h0     = (4u - galign) & 3u;                  // head scalars
    const unsigned bbeg   = lbeg + h0;                           // aligned body start
    const unsigned bspan  = (lend > bbeg) ? ((lend - bbeg) & ~3u) : 0u;
    const unsigned bend   = bbeg + bspan;
    const unsigned tcount = lend - bend;                         // tail scalars (0..3)

    // head (lanes 0..h0-1) and tail (lanes 64..64+tcount-1) — one-time scalars
    if (tid < h0) {
        const unsigned e = lbeg + tid;
        const unsigned i = e / NP;
        const unsigned j = e - i * NP;
        out[gofs + e] = cpb_val(sP, i, j);
    }
    if (tid >= 64u && tid < 64u + tcount) {
        const unsigned e = bend + (tid - 64u);
        const unsigned i = e / NP;
        const unsigned j = e - i * NP;
        out[gofs + e] = cpb_val(sP, i, j);
    }

    // aligned float4 body
    const unsigned ngroups = bspan >> 2;                         // <= 10405
    for (unsigned g = tid; g < ngroups; g += 512u) {
        const unsigned e0 = bbeg + (g << 2);
        unsigned i = e0 / NP;                                    // magic-mul
        unsigned j = e0 - i * NP;
        float4 o;
#pragma unroll
        for (int d = 0; d < 4; ++d) {
            (&o.x)[d] = cpb_val(sP, i, j);
            if (++j == (unsigned)NP) { j = 0u; ++i; }
        }
        *reinterpret_cast<float4*>(out + gofs + e0) = o;
    }
}

// ---------------------------------------------------------------------------
extern "C" void kernel_launch(void* const* d_in, const int* in_sizes, int n_in,
                              void* d_out, int out_size, void* d_ws, size_t ws_size,
                              hipStream_t stream)
{
    const float* glob_pos     = (const float*)d_in[0];
    const float* coords_table = (const float*)d_in[1];
    // d_in[2] = rpi — unused (index computed analytically in stage 2)
    const float* W1           = (const float*)d_in[3];
    const float* b1           = (const float*)d_in[4];
    const float* W2           = (const float*)d_in[5];
    // d_in[6] = num_prefix_tokens (always 1; NP/PLANE are compile-time)

    float* out    = (float*)d_out;
    float* bias_t = (float*)d_ws;   // 32*16*2209 floats = 4.5 MB scratch

    // Stage 1: 32*2209 = 70,688 threads
    const int n1 = NB * TT;
    const int blocks1 = (n1 + 255) / 256;
    cpb_mlp<<<blocks1, 256, 0, stream>>>(glob_pos, coords_table, W1, b1, W2, bias_t);

    // Stage 2: 512 planes x 8 chunks, 512 threads
    const unsigned blocks2 = (unsigned)NB * NH * 8u;   // 4096
    cpb_scatter<<<blocks2, 512, 0, stream>>>(bias_t, out);
}

// Round 13
// 755.044 us; speedup vs baseline: 1.0938x; 1.0938x over previous
//
#include <hip/hip_runtime.h>
#include <hip/hip_bf16.h>

// Problem constants (fixed by setup_inputs)
#define TT    2209          // 47*47 relative-position table entries
#define NB    32            // batch
#define NH    16            // heads
#define ND    512           // RPB hidden dim
#define WH    24            // window height/width
#define NW    576           // 24*24 window tokens
#define NP    577           // NW + num_prefix_tokens(=1)
#define PLANE (NP * NP)     // 332929 floats per (b,h) output plane

// padded LDS layout: element x lives at x + (x>>5)  (one pad word per 32)
// -> a stride-4 descending gather rotates across all 32 banks (~2-way = free)
#define PADSZ 2304          // >= 2208 + (2208>>5) + 1 = 2278

__device__ __forceinline__ unsigned pidx(unsigned x) { return x + (x >> 5); }

// ---------------------------------------------------------------------------
// Stage 1: bias_t[b][h][t] = (relu((coords_table[t] + pos[b]) @ W1 + b1) @ W2)[h]
// (unchanged from the measured 730/733 µs runs)
// ---------------------------------------------------------------------------
__global__ __launch_bounds__(256) void cpb_mlp(
    const float* __restrict__ glob_pos,     // (1, 32, 4)
    const float* __restrict__ coords_table, // (2209, 2)
    const float* __restrict__ W1,           // (2, 512)
    const float* __restrict__ b1,           // (512,)
    const float* __restrict__ W2,           // (512, 16)
    float* __restrict__ bias_t)             // (32, 16, 2209) scratch
{
    __shared__ float sW13[ND][4];           // {W1row0, W1row1, b1, pad} — 8 KB
    __shared__ float sW2[ND][NH];           // 32 KB

    const int tid = threadIdx.x;
    for (int d = tid; d < ND; d += 256) {
        float4 v;
        v.x = W1[d];            // W1[0][d]
        v.y = W1[ND + d];       // W1[1][d]
        v.z = b1[d];
        v.w = 0.0f;
        *reinterpret_cast<float4*>(&sW13[d][0]) = v;
    }
    for (int i = tid; i < ND * NH / 4; i += 256) {
        reinterpret_cast<float4*>(&sW2[0][0])[i] =
            reinterpret_cast<const float4*>(W2)[i];
    }
    __syncthreads();

    const unsigned gid  = blockIdx.x * 256u + tid;
    const bool     live = gid < (unsigned)(NB * TT);
    const unsigned b    = live ? gid / TT : 0u;
    const unsigned t    = live ? gid - b * TT : 0u;

    const float g0 = glob_pos[b * 4 + 0];
    const float g1 = glob_pos[b * 4 + 1];
    const float g2 = glob_pos[b * 4 + 2];
    const float g3 = glob_pos[b * 4 + 3];
    float px = g2 / g0 * 8.0f;
    float py = g3 / g1 * 8.0f;
    px = copysignf(log2f(fabsf(px) + 1.0f) * (1.0f / 3.0f), px) * 2.0f - 1.0f;
    py = copysignf(log2f(fabsf(py) + 1.0f) * (1.0f / 3.0f), py) * 2.0f - 1.0f;

    const float tx = coords_table[t * 2 + 0] + px;
    const float ty = coords_table[t * 2 + 1] + py;

    float acc[NH];
#pragma unroll
    for (int h = 0; h < NH; ++h) acc[h] = 0.0f;

#pragma unroll 1
    for (int d0 = 0; d0 < ND; d0 += 4) {
        float hv[4];
#pragma unroll
        for (int k = 0; k < 4; ++k) {
            const float4 w = *reinterpret_cast<const float4*>(&sW13[d0 + k][0]);
            hv[k] = fmaxf(fmaf(tx, w.x, fmaf(ty, w.y, w.z)), 0.0f);
        }
#pragma unroll
        for (int k = 0; k < 4; ++k) {
            const float4 w0 = *reinterpret_cast<const float4*>(&sW2[d0 + k][0]);
            const float4 w1 = *reinterpret_cast<const float4*>(&sW2[d0 + k][4]);
            const float4 w2 = *reinterpret_cast<const float4*>(&sW2[d0 + k][8]);
            const float4 w3 = *reinterpret_cast<const float4*>(&sW2[d0 + k][12]);
            acc[0]  = fmaf(hv[k], w0.x, acc[0]);   acc[1]  = fmaf(hv[k], w0.y, acc[1]);
            acc[2]  = fmaf(hv[k], w0.z, acc[2]);   acc[3]  = fmaf(hv[k], w0.w, acc[3]);
            acc[4]  = fmaf(hv[k], w1.x, acc[4]);   acc[5]  = fmaf(hv[k], w1.y, acc[5]);
            acc[6]  = fmaf(hv[k], w1.z, acc[6]);   acc[7]  = fmaf(hv[k], w1.w, acc[7]);
            acc[8]  = fmaf(hv[k], w2.x, acc[8]);   acc[9]  = fmaf(hv[k], w2.y, acc[9]);
            acc[10] = fmaf(hv[k], w2.z, acc[10]);  acc[11] = fmaf(hv[k], w2.w, acc[11]);
            acc[12] = fmaf(hv[k], w3.x, acc[12]);  acc[13] = fmaf(hv[k], w3.y, acc[13]);
            acc[14] = fmaf(hv[k], w3.z, acc[14]);  acc[15] = fmaf(hv[k], w3.w, acc[15]);
        }
    }

    if (live) {
#pragma unroll
        for (int h = 0; h < NH; ++h) {
            bias_t[(b * NH + h) * TT + t] = acc[h];
        }
    }
}

// ---------------------------------------------------------------------------
// Stage 2: identical to the 733 µs R11 kernel EXCEPT the LDS layout is
// padded (x -> x + (x>>5)) to break the 8-way stride-4 gather bank conflict.
// Each block owns a contiguous 41,984-element flat range (spans at most one
// plane boundary); both touchable planes are staged in LDS once per block.
// idx computed analytically: (qh-kh+23)*47 + (qw-kw+23).
// ---------------------------------------------------------------------------
#define VPT   41u                       // float4 groups per thread
#define GPB   (256u * VPT)              // groups per block
#define EPB   (GPB * 4u)                // elements per block = 41984 (< PLANE)

__global__ __launch_bounds__(256) void cpb_scatter(
    const float* __restrict__ bias_t, // (32, 16, 2209)
    float* __restrict__ out)          // (32, 16, 577, 577) flat
{
    constexpr unsigned TOTAL = (unsigned)NB * NH * PLANE; // 170,459,648 (div 4)

    const unsigned bx    = blockIdx.x;
    const unsigned tid   = threadIdx.x;
    const unsigned ebase = bx * EPB;
    if (ebase >= TOTAL) return;                 // whole block OOB (uniform)

    __shared__ float sA[PADSZ];                 // first plane (padded layout)
    __shared__ float sB[PADSZ];                 // last plane  (padded layout)

    const unsigned eend = min(ebase + EPB, TOTAL);
    const unsigned pA   = ebase / PLANE;
    const unsigned pB   = (eend - 1u) / PLANE;  // pA or pA+1, <= 511
    const float* __restrict__ plA = bias_t + (size_t)pA * TT;
    const float* __restrict__ plB = bias_t + (size_t)pB * TT;
    for (unsigned x = tid; x < (unsigned)TT; x += 256u) {
        sA[pidx(x)] = plA[x];
        sB[pidx(x)] = plB[x];
    }
    __syncthreads();

#pragma unroll 2
    for (unsigned k = 0; k < VPT; ++k) {
        const unsigned off = ebase + (k * 256u + tid) * 4u;
        if (off < TOTAL) {
            const unsigned p0   = off / PLANE;          // magic-mul
            const unsigned rem0 = off - p0 * PLANE;
            float4 o;
#pragma unroll
            for (int d = 0; d < 4; ++d) {
                unsigned pp = p0;
                unsigned ee = rem0 + (unsigned)d;
                if (ee >= (unsigned)PLANE) { ee -= (unsigned)PLANE; ++pp; }
                const float* __restrict__ s = (pp == pA) ? sA : sB;
                const unsigned i = ee / NP;             // magic-mul
                const unsigned j = ee - i * NP;
                float v = 0.0f;
                if (i != 0u && j != 0u) {
                    const unsigned q  = i - 1u;
                    const unsigned kk = j - 1u;
                    const unsigned qh = q / WH,  qw = q - qh * WH;
                    const unsigned kh = kk / WH, kw = kk - kh * WH;
                    v = s[pidx((qh - kh + (WH - 1u)) * (2u * WH - 1u)
                               + (qw - kw + (WH - 1u)))];
                }
                (&o.x)[d] = v;
            }
            *reinterpret_cast<float4*>(out + off) = o;   // plain float4 store
        }
    }
}

// ---------------------------------------------------------------------------
extern "C" void kernel_launch(void* const* d_in, const int* in_sizes, int n_in,
                              void* d_out, int out_size, void* d_ws, size_t ws_size,
                              hipStream_t stream)
{
    const float* glob_pos     = (const float*)d_in[0];
    const float* coords_table = (const float*)d_in[1];
    // d_in[2] = rpi — unused (index computed analytically in stage 2)
    const float* W1           = (const float*)d_in[3];
    const float* b1           = (const float*)d_in[4];
    const float* W2           = (const float*)d_in[5];
    // d_in[6] = num_prefix_tokens (always 1; NP/PLANE are compile-time)

    float* out    = (float*)d_out;
    float* bias_t = (float*)d_ws;   // 32*16*2209 floats = 4.5 MB scratch

    // Stage 1: 32*2209 = 70,688 threads
    const int n1 = NB * TT;
    const int blocks1 = (n1 + 255) / 256;
    cpb_mlp<<<blocks1, 256, 0, stream>>>(glob_pos, coords_table, W1, b1, W2, bias_t);

    // Stage 2: contiguous flat ranges, 41,984 elems / block
    constexpr unsigned TOTAL  = (unsigned)NB * NH * PLANE;
    const unsigned blocks2 = (TOTAL + EPB - 1u) / EPB;   // 4061
    cpb_scatter<<<blocks2, 256, 0, stream>>>(bias_t, out);
}

// Round 16
// 739.997 us; speedup vs baseline: 1.1160x; 1.0203x over previous
//
#include <hip/hip_runtime.h>
#include <hip/hip_bf16.h>

// Problem constants (fixed by setup_inputs)
#define TT    2209          // 47*47 relative-position table entries
#define NB    32            // batch
#define NH    16            // heads
#define ND    512           // RPB hidden dim
#define WH    24            // window height/width
#define NW    576           // 24*24 window tokens
#define NP    577           // NW + num_prefix_tokens(=1)
#define PLANE (NP * NP)     // 332929 floats per (b,h) output plane

// ---------------------------------------------------------------------------
// Stage 1: bias_t[b][h][t] = (relu((coords_table[t] + pos[b]) @ W1 + b1) @ W2)[h]
// Weights staged in LDS; all weight reads are wave-uniform broadcasts
// (conflict-free). Head-major output so stage 2's gathers for one plane are
// one contiguous 8.8 KB block.
// ---------------------------------------------------------------------------
__global__ __launch_bounds__(256) void cpb_mlp(
    const float* __restrict__ glob_pos,     // (1, 32, 4)
    const float* __restrict__ coords_table, // (2209, 2)
    const float* __restrict__ W1,           // (2, 512)
    const float* __restrict__ b1,           // (512,)
    const float* __restrict__ W2,           // (512, 16)
    float* __restrict__ bias_t)             // (32, 16, 2209) scratch
{
    __shared__ float sW13[ND][4];           // {W1row0, W1row1, b1, pad} — 8 KB
    __shared__ float sW2[ND][NH];           // 32 KB

    const int tid = threadIdx.x;
    for (int d = tid; d < ND; d += 256) {
        float4 v;
        v.x = W1[d];            // W1[0][d]
        v.y = W1[ND + d];       // W1[1][d]
        v.z = b1[d];
        v.w = 0.0f;
        *reinterpret_cast<float4*>(&sW13[d][0]) = v;
    }
    for (int i = tid; i < ND * NH / 4; i += 256) {
        reinterpret_cast<float4*>(&sW2[0][0])[i] =
            reinterpret_cast<const float4*>(W2)[i];
    }
    __syncthreads();

    const unsigned gid  = blockIdx.x * 256u + tid;
    const bool     live = gid < (unsigned)(NB * TT);
    const unsigned b    = live ? gid / TT : 0u;
    const unsigned t    = live ? gid - b * TT : 0u;

    const float g0 = glob_pos[b * 4 + 0];
    const float g1 = glob_pos[b * 4 + 1];
    const float g2 = glob_pos[b * 4 + 2];
    const float g3 = glob_pos[b * 4 + 3];
    float px = g2 / g0 * 8.0f;
    float py = g3 / g1 * 8.0f;
    px = copysignf(log2f(fabsf(px) + 1.0f) * (1.0f / 3.0f), px) * 2.0f - 1.0f;
    py = copysignf(log2f(fabsf(py) + 1.0f) * (1.0f / 3.0f), py) * 2.0f - 1.0f;

    const float tx = coords_table[t * 2 + 0] + px;
    const float ty = coords_table[t * 2 + 1] + py;

    float acc[NH];
#pragma unroll
    for (int h = 0; h < NH; ++h) acc[h] = 0.0f;

#pragma unroll 1
    for (int d0 = 0; d0 < ND; d0 += 4) {
        float hv[4];
#pragma unroll
        for (int k = 0; k < 4; ++k) {
            const float4 w = *reinterpret_cast<const float4*>(&sW13[d0 + k][0]);
            hv[k] = fmaxf(fmaf(tx, w.x, fmaf(ty, w.y, w.z)), 0.0f);
        }
#pragma unroll
        for (int k = 0; k < 4; ++k) {
            const float4 w0 = *reinterpret_cast<const float4*>(&sW2[d0 + k][0]);
            const float4 w1 = *reinterpret_cast<const float4*>(&sW2[d0 + k][4]);
            const float4 w2 = *reinterpret_cast<const float4*>(&sW2[d0 + k][8]);
            const float4 w3 = *reinterpret_cast<const float4*>(&sW2[d0 + k][12]);
            acc[0]  = fmaf(hv[k], w0.x, acc[0]);   acc[1]  = fmaf(hv[k], w0.y, acc[1]);
            acc[2]  = fmaf(hv[k], w0.z, acc[2]);   acc[3]  = fmaf(hv[k], w0.w, acc[3]);
            acc[4]  = fmaf(hv[k], w1.x, acc[4]);   acc[5]  = fmaf(hv[k], w1.y, acc[5]);
            acc[6]  = fmaf(hv[k], w1.z, acc[6]);   acc[7]  = fmaf(hv[k], w1.w, acc[7]);
            acc[8]  = fmaf(hv[k], w2.x, acc[8]);   acc[9]  = fmaf(hv[k], w2.y, acc[9]);
            acc[10] = fmaf(hv[k], w2.z, acc[10]);  acc[11] = fmaf(hv[k], w2.w, acc[11]);
            acc[12] = fmaf(hv[k], w3.x, acc[12]);  acc[13] = fmaf(hv[k], w3.y, acc[13]);
            acc[14] = fmaf(hv[k], w3.z, acc[14]);  acc[15] = fmaf(hv[k], w3.w, acc[15]);
        }
    }

    if (live) {
#pragma unroll
        for (int h = 0; h < NH; ++h) {
            bias_t[(b * NH + h) * TT + t] = acc[h];
        }
    }
}

// ---------------------------------------------------------------------------
// Stage 2: out[flat] — float4 plain store stream (best-measured structure,
// 733.0 µs in Round 11). Each block owns a contiguous 41,984-element flat
// range (spans at most one plane boundary); both touchable planes are staged
// in LDS once per block. idx computed analytically:
// (qh-kh+23)*47 + (qw-kw+23).
// ---------------------------------------------------------------------------
#define VPT   41u                       // float4 groups per thread
#define GPB   (256u * VPT)              // groups per block
#define EPB   (GPB * 4u)                // elements per block = 41984 (< PLANE)

__global__ __launch_bounds__(256) void cpb_scatter(
    const float* __restrict__ bias_t, // (32, 16, 2209)
    float* __restrict__ out)          // (32, 16, 577, 577) flat
{
    constexpr unsigned TOTAL = (unsigned)NB * NH * PLANE; // 170,459,648 (div 4)

    const unsigned bx    = blockIdx.x;
    const unsigned tid   = threadIdx.x;
    const unsigned ebase = bx * EPB;
    if (ebase >= TOTAL) return;                 // whole block OOB (uniform)

    __shared__ float sA[TT];                    // first plane this block touches
    __shared__ float sB[TT];                    // last plane (== first if no cross)

    const unsigned eend = min(ebase + EPB, TOTAL);
    const unsigned pA   = ebase / PLANE;
    const unsigned pB   = (eend - 1u) / PLANE;  // pA or pA+1, <= 511
    const float* __restrict__ plA = bias_t + (size_t)pA * TT;
    const float* __restrict__ plB = bias_t + (size_t)pB * TT;
    for (unsigned x = tid; x < (unsigned)TT; x += 256u) {
        sA[x] = plA[x];
        sB[x] = plB[x];
    }
    __syncthreads();

#pragma unroll 2
    for (unsigned k = 0; k < VPT; ++k) {
        const unsigned off = ebase + (k * 256u + tid) * 4u;
        if (off < TOTAL) {
            const unsigned p0   = off / PLANE;          // magic-mul
            const unsigned rem0 = off - p0 * PLANE;
            float4 o;
#pragma unroll
            for (int d = 0; d < 4; ++d) {
                unsigned pp = p0;
                unsigned ee = rem0 + (unsigned)d;
                if (ee >= (unsigned)PLANE) { ee -= (unsigned)PLANE; ++pp; }
                const float* __restrict__ s = (pp == pA) ? sA : sB;
                const unsigned i = ee / NP;             // magic-mul
                const unsigned j = ee - i * NP;
                float v = 0.0f;
                if (i != 0u && j != 0u) {
                    const unsigned q  = i - 1u;
                    const unsigned kk = j - 1u;
                    const unsigned qh = q / WH,  qw = q - qh * WH;
                    const unsigned kh = kk / WH, kw = kk - kh * WH;
                    v = s[(qh - kh + (WH - 1u)) * (2u * WH - 1u)
                          + (qw - kw + (WH - 1u))];
                }
                (&o.x)[d] = v;
            }
            *reinterpret_cast<float4*>(out + off) = o;   // plain float4 store
        }
    }
}

// ---------------------------------------------------------------------------
extern "C" void kernel_launch(void* const* d_in, const int* in_sizes, int n_in,
                              void* d_out, int out_size, void* d_ws, size_t ws_size,
                              hipStream_t stream)
{
    const float* glob_pos     = (const float*)d_in[0];
    const float* coords_table = (const float*)d_in[1];
    // d_in[2] = rpi — unused (index computed analytically in stage 2)
    const float* W1           = (const float*)d_in[3];
    const float* b1           = (const float*)d_in[4];
    const float* W2           = (const float*)d_in[5];
    // d_in[6] = num_prefix_tokens (always 1; NP/PLANE are compile-time)

    float* out    = (float*)d_out;
    float* bias_t = (float*)d_ws;   // 32*16*2209 floats = 4.5 MB scratch

    // Stage 1: 32*2209 = 70,688 threads
    const int n1 = NB * TT;
    const int blocks1 = (n1 + 255) / 256;
    cpb_mlp<<<blocks1, 256, 0, stream>>>(glob_pos, coords_table, W1, b1, W2, bias_t);

    // Stage 2: contiguous flat ranges, 41,984 elems / block
    constexpr unsigned TOTAL  = (unsigned)NB * NH * PLANE;
    const unsigned blocks2 = (TOTAL + EPB - 1u) / EPB;   // 4061
    cpb_scatter<<<blocks2, 256, 0, stream>>>(bias_t, out);
}